// Round 7
// baseline (1426.156 us; speedup 1.0000x reference)
//
#include <hip/hip_runtime.h>
#include <hip/hip_bf16.h>
#include <math.h>

// ======== DIAGNOSTIC ROUND: k1 body x6, k3 body x16 (idempotent repeats) ====
// Purpose: k1 dispatches become the top-5 rocprof rows (fills are ~157us) so
// we finally read k1's own FETCH/VALUBusy/Occupancy; k3 cost falls out of
// dur arithmetic: dur - 137 = 5*k1 + 15*k3. Output remains bit-identical.
#define REP_K1 6
#define REP_K3 16

#define TT 4096
#define BB 32
#define HH 512
#define CC 32000
#define NCHUNK 64   // t-chunks (TT/TPC)
#define TPC 64      // t per chunk (4 waves x 16 rows)

// ws layout (float offsets)
#define WS_CTX    0          // 32*512 = 16384 floats (k2->k3)
#define WS_LPART  16384      // 32*64 = 2048 floats (k1->k2)
#define WS_BIG    18432      // ctx_part 32*64*512=1,048,576 f; then out_part 2*32*32000=2,048,000 f

__device__ __forceinline__ float dot4(const float4 a, const float4 b) {
  return fmaf(a.w, b.w, fmaf(a.z, b.z, fmaf(a.y, b.y, fmaf(a.x, b.x, 0.f))));
}

// ---------------- k1: fused score + weighted partial sums (x REP_K1) -------
__global__ __launch_bounds__(256) void k1_partials(
    const float* __restrict__ dec, const float* __restrict__ aw,
    const float* __restrict__ abp,
    float* __restrict__ ctx_part, float* __restrict__ l_part)
{
  const int chunk = blockIdx.x;
  const int b     = blockIdx.y;
  const int tid   = threadIdx.x;
  const int wv = tid >> 6, ln = tid & 63;
  const float ab = abp[0];
  const float4 aw0 = *(const float4*)(aw + ln*4);          // h in [0,256)
  const float4 aw1 = *(const float4*)(aw + 256 + ln*4);    // h in [256,512)

  const size_t rowstep = (size_t)BB*HH;
  const float* base = dec + ((size_t)(chunk*TPC + wv*16)*BB + b)*HH + (size_t)ln*4;

  __shared__ float s_ctx[4][HH];
  __shared__ float s_l[4];

  for (int rep = 0; rep < REP_K1; ++rep) {
    float4 c0 = make_float4(0.f,0.f,0.f,0.f), c1 = make_float4(0.f,0.f,0.f,0.f);
    float l = 0.f;

    for (int it = 0; it < 16; it += 2) {
      const float* p0 = base + (size_t)it*rowstep;
      const float* p1 = base + (size_t)(it+1)*rowstep;
      const float4 xa0 = *(const float4*)(p0);
      const float4 xa1 = *(const float4*)(p0 + 256);
      const float4 xb0 = *(const float4*)(p1);
      const float4 xb1 = *(const float4*)(p1 + 256);
      float da = dot4(xa0, aw0) + dot4(xa1, aw1);
      float db = dot4(xb0, aw0) + dot4(xb1, aw1);
      #pragma unroll
      for (int off = 32; off > 0; off >>= 1) {
        da += __shfl_xor(da, off);
        db += __shfl_xor(db, off);
      }
      const float exa = __expf(2.f*(da + ab));
      const float exb = __expf(2.f*(db + ab));
      const float tha = 1.f - 2.f*__builtin_amdgcn_rcpf(exa + 1.f);
      const float thb = 1.f - 2.f*__builtin_amdgcn_rcpf(exb + 1.f);
      const float wa = __expf(tha);
      const float wb = __expf(thb);
      l += wa + wb;
      c0.x = fmaf(wa, xa0.x, fmaf(wb, xb0.x, c0.x));
      c0.y = fmaf(wa, xa0.y, fmaf(wb, xb0.y, c0.y));
      c0.z = fmaf(wa, xa0.z, fmaf(wb, xb0.z, c0.z));
      c0.w = fmaf(wa, xa0.w, fmaf(wb, xb0.w, c0.w));
      c1.x = fmaf(wa, xa1.x, fmaf(wb, xb1.x, c1.x));
      c1.y = fmaf(wa, xa1.y, fmaf(wb, xb1.y, c1.y));
      c1.z = fmaf(wa, xa1.z, fmaf(wb, xb1.z, c1.z));
      c1.w = fmaf(wa, xa1.w, fmaf(wb, xb1.w, c1.w));
    }

    *(float4*)&s_ctx[wv][ln*4]       = c0;
    *(float4*)&s_ctx[wv][256 + ln*4] = c1;
    if (ln == 0) s_l[wv] = l;
    __syncthreads();
    if (tid < 128) {
      const int h = tid * 4;
      float4 a = make_float4(0.f,0.f,0.f,0.f);
      #pragma unroll
      for (int w2 = 0; w2 < 4; ++w2) {
        const float4 v = *(const float4*)&s_ctx[w2][h];
        a.x += v.x; a.y += v.y; a.z += v.z; a.w += v.w;
      }
      const size_t pp = (size_t)b*NCHUNK + chunk;
      *(float4*)(ctx_part + pp*HH + h) = a;
      if (tid == 0) l_part[pp] = s_l[0] + s_l[1] + s_l[2] + s_l[3];
    }
    __syncthreads();   // s_ctx safe to rewrite next rep
  }
}

// ---------------- k2: combine partials -> normalized context ----------------
__global__ __launch_bounds__(128) void k2_combine(
    const float* __restrict__ ctx_part, const float* __restrict__ l_part,
    float* __restrict__ ctx)
{
  const int b = blockIdx.x;
  const int h = threadIdx.x * 4;
  float L = 0.f;
  for (int p = 0; p < NCHUNK; ++p) L += l_part[b*NCHUNK + p];
  float4 a = make_float4(0.f,0.f,0.f,0.f);
  for (int p = 0; p < NCHUNK; ++p) {
    const float4 v = *(const float4*)(ctx_part + ((size_t)b*NCHUNK + p)*HH + h);
    a.x += v.x; a.y += v.y; a.z += v.z; a.w += v.w;
  }
  const float inv = 1.f / L;
  *(float4*)(ctx + b*HH + h) = make_float4(a.x*inv, a.y*inv, a.z*inv, a.w*inv);
}

// ---------------- k3: out = ctx @ out_w^T (x REP_K3) ------------------------
__global__ __launch_bounds__(128) void k3_matmul(
    const float* __restrict__ ctx, const float* __restrict__ ow,
    float* __restrict__ out_part)
{
  const int c = blockIdx.x * 128 + threadIdx.x;
  const int half = blockIdx.y;            // h in [half*256, half*256+256)
  const int h0 = half * 256;
  const float* wrow = ow + (size_t)c * HH + h0;
  const float* cb = ctx + h0;             // uniform across block
  for (int rep = 0; rep < REP_K3; ++rep) {
    float acc[BB];
    #pragma unroll
    for (int b = 0; b < BB; ++b) acc[b] = 0.f;
    for (int hh = 0; hh < 256; hh += 4) {
      const float4 w4 = *(const float4*)(wrow + hh);
      #pragma unroll
      for (int b = 0; b < BB; ++b) {
        const float4 c4 = *(const float4*)(cb + (size_t)b*HH + hh);
        acc[b] = fmaf(w4.w, c4.w, fmaf(w4.z, c4.z, fmaf(w4.y, c4.y, fmaf(w4.x, c4.x, acc[b]))));
      }
    }
    float* op = out_part + (size_t)half * ((size_t)BB*CC);
    #pragma unroll
    for (int b = 0; b < BB; ++b) op[(size_t)b*CC + c] = acc[b];
  }
}

// ---------------- k4: sum halves + bias -> d_out ---------------------------
__global__ __launch_bounds__(256) void k4_final(
    const float* __restrict__ out_part, const float* __restrict__ ob,
    float* __restrict__ out)
{
  const size_t i = ((size_t)blockIdx.x * 256 + threadIdx.x) * 4;
  const float4 p0 = *(const float4*)(out_part + i);
  const float4 p1 = *(const float4*)(out_part + (size_t)BB*CC + i);
  const int cIdx = (int)(i % CC);
  const float4 b4 = *(const float4*)(ob + cIdx);
  const float4 r = make_float4(p0.x+p1.x+b4.x, p0.y+p1.y+b4.y,
                               p0.z+p1.z+b4.z, p0.w+p1.w+b4.w);
  *(float4*)(out + i) = r;
}

extern "C" void kernel_launch(void* const* d_in, const int* in_sizes, int n_in,
                              void* d_out, int out_size, void* d_ws, size_t ws_size,
                              hipStream_t stream) {
  const float* dec = (const float*)d_in[0];
  const float* aw  = (const float*)d_in[1];
  const float* ab  = (const float*)d_in[2];
  const float* ow  = (const float*)d_in[3];
  const float* ob  = (const float*)d_in[4];
  float* out = (float*)d_out;
  float* ws  = (float*)d_ws;
  float* ctx   = ws + WS_CTX;
  float* lpart = ws + WS_LPART;
  float* big   = ws + WS_BIG;   // ctx_part for k1/k2, reused as out_part for k3/k4

  k1_partials<<<dim3(NCHUNK, BB), 256, 0, stream>>>(dec, aw, ab, big, lpart);
  k2_combine<<<dim3(BB), 128, 0, stream>>>(big, lpart, ctx);
  k3_matmul<<<dim3(CC/128, 2), 128, 0, stream>>>(ctx, ow, big);
  k4_final<<<dim3((BB*CC)/(256*4)), 256, 0, stream>>>(big, ob, out);
}

// Round 8
// 114.986 us; speedup vs baseline: 12.4029x; 12.4029x over previous
//
#include <hip/hip_runtime.h>
#include <hip/hip_bf16.h>
#include <math.h>

#define TT 4096
#define BB 32
#define HH 512
#define CC 32000
#define NCHUNK 64   // t-chunks (TT/TPC)
#define TPC 64      // t per chunk (4 waves x 16 rows)
#define HS 8        // h-slices in k3 (64 h each)
#define OSLICE (BB*CC)  // 1,024,000

// ws layout (float offsets)
#define WS_CTX    0          // 16384 floats (k2->k3)
#define WS_LPART  16384      // 2048 floats (k1->k2)
#define WS_BIG    18432      // cpart 1,048,576 f (k1->k2); then opart 8*1,024,000 f (k3->k4)

__device__ __forceinline__ float dot4(const float4 a, const float4 b) {
  return fmaf(a.w, b.w, fmaf(a.z, b.z, fmaf(a.y, b.y, fmaf(a.x, b.x, 0.f))));
}

// ---------------- k1: fused score + weighted partial sums ------------------
// (R6 verbatim -- measured ~33us, near its 40us HBM floor. Do not touch.)
__global__ __launch_bounds__(256) void k1_partials(
    const float* __restrict__ dec, const float* __restrict__ aw,
    const float* __restrict__ abp,
    float* __restrict__ ctx_part, float* __restrict__ l_part)
{
  const int chunk = blockIdx.x;
  const int b     = blockIdx.y;
  const int tid   = threadIdx.x;
  const int wv = tid >> 6, ln = tid & 63;
  const float ab = abp[0];
  const float4 aw0 = *(const float4*)(aw + ln*4);          // h in [0,256)
  const float4 aw1 = *(const float4*)(aw + 256 + ln*4);    // h in [256,512)

  const size_t rowstep = (size_t)BB*HH;
  const float* base = dec + ((size_t)(chunk*TPC + wv*16)*BB + b)*HH + (size_t)ln*4;

  float4 c0 = make_float4(0.f,0.f,0.f,0.f), c1 = make_float4(0.f,0.f,0.f,0.f);
  float l = 0.f;

  for (int it = 0; it < 16; it += 2) {
    const float* p0 = base + (size_t)it*rowstep;
    const float* p1 = base + (size_t)(it+1)*rowstep;
    const float4 xa0 = *(const float4*)(p0);
    const float4 xa1 = *(const float4*)(p0 + 256);
    const float4 xb0 = *(const float4*)(p1);
    const float4 xb1 = *(const float4*)(p1 + 256);
    float da = dot4(xa0, aw0) + dot4(xa1, aw1);
    float db = dot4(xb0, aw0) + dot4(xb1, aw1);
    #pragma unroll
    for (int off = 32; off > 0; off >>= 1) {
      da += __shfl_xor(da, off);
      db += __shfl_xor(db, off);
    }
    const float exa = __expf(2.f*(da + ab));
    const float exb = __expf(2.f*(db + ab));
    const float tha = 1.f - 2.f*__builtin_amdgcn_rcpf(exa + 1.f);
    const float thb = 1.f - 2.f*__builtin_amdgcn_rcpf(exb + 1.f);
    const float wa = __expf(tha);
    const float wb = __expf(thb);
    l += wa + wb;
    c0.x = fmaf(wa, xa0.x, fmaf(wb, xb0.x, c0.x));
    c0.y = fmaf(wa, xa0.y, fmaf(wb, xb0.y, c0.y));
    c0.z = fmaf(wa, xa0.z, fmaf(wb, xb0.z, c0.z));
    c0.w = fmaf(wa, xa0.w, fmaf(wb, xb0.w, c0.w));
    c1.x = fmaf(wa, xa1.x, fmaf(wb, xb1.x, c1.x));
    c1.y = fmaf(wa, xa1.y, fmaf(wb, xb1.y, c1.y));
    c1.z = fmaf(wa, xa1.z, fmaf(wb, xb1.z, c1.z));
    c1.w = fmaf(wa, xa1.w, fmaf(wb, xb1.w, c1.w));
  }

  __shared__ float s_ctx[4][HH];
  __shared__ float s_l[4];
  *(float4*)&s_ctx[wv][ln*4]       = c0;
  *(float4*)&s_ctx[wv][256 + ln*4] = c1;
  if (ln == 0) s_l[wv] = l;
  __syncthreads();
  if (tid < 128) {
    const int h = tid * 4;
    float4 a = make_float4(0.f,0.f,0.f,0.f);
    #pragma unroll
    for (int w2 = 0; w2 < 4; ++w2) {
      const float4 v = *(const float4*)&s_ctx[w2][h];
      a.x += v.x; a.y += v.y; a.z += v.z; a.w += v.w;
    }
    const size_t pp = (size_t)b*NCHUNK + chunk;
    *(float4*)(ctx_part + pp*HH + h) = a;
    if (tid == 0) l_part[pp] = s_l[0] + s_l[1] + s_l[2] + s_l[3];
  }
}

// ---------------- k2: combine partials -> normalized context ----------------
__global__ __launch_bounds__(128) void k2_combine(
    const float* __restrict__ ctx_part, const float* __restrict__ l_part,
    float* __restrict__ ctx)
{
  const int b = blockIdx.x;
  const int h = threadIdx.x * 4;
  float L = 0.f;
  for (int p = 0; p < NCHUNK; ++p) L += l_part[b*NCHUNK + p];
  float4 a = make_float4(0.f,0.f,0.f,0.f);
  for (int p = 0; p < NCHUNK; ++p) {
    const float4 v = *(const float4*)(ctx_part + ((size_t)b*NCHUNK + p)*HH + h);
    a.x += v.x; a.y += v.y; a.z += v.z; a.w += v.w;
  }
  const float inv = 1.f / L;
  *(float4*)(ctx + b*HH + h) = make_float4(a.x*inv, a.y*inv, a.z*inv, a.w*inv);
}

// ---------------- k3: register-tiled GEMM  opart[hs][b][c] ------------------
// Old k3 was L1-BW-bound: thread-per-c re-read all of ctx -> 2.1 TB via L1,
// at 2 waves/CU. Now: thread owns 4c x 16b tile for one (h-slice, b-half):
// ctx traffic /4 (512MB), waves 500 -> 2048 (8/CU). ctx slice [16][64]
// (4KB) in LDS; reads are wave-uniform -> broadcast, conflict-free.
__global__ __launch_bounds__(256) void k3_matmul(
    const float* __restrict__ ctx, const float* __restrict__ ow,
    float* __restrict__ out_part)
{
  __shared__ float lds[16*64];
  const int tid = threadIdx.x;
  const int hs = blockIdx.y, bh = blockIdx.z;
  const int h0 = hs*64;
  {
    const int j = tid*4, bi = j >> 6, hh = j & 63;
    *(float4*)&lds[j] = *(const float4*)(ctx + (size_t)(bh*16+bi)*HH + h0 + hh);
  }
  __syncthreads();

  const int c0 = blockIdx.x*1024 + tid;
  const float* wp[4];
  int cc[4];
  #pragma unroll
  for (int g = 0; g < 4; ++g) {
    cc[g] = c0 + g*256;
    const int cs = cc[g] < CC ? cc[g] : CC-1;   // clamp loads; store guarded
    wp[g] = ow + (size_t)cs*HH + h0;
  }

  float acc[4][16];
  #pragma unroll
  for (int g = 0; g < 4; ++g)
    #pragma unroll
    for (int bi = 0; bi < 16; ++bi) acc[g][bi] = 0.f;

  for (int hh = 0; hh < 64; hh += 4) {
    float4 w4[4];
    #pragma unroll
    for (int g = 0; g < 4; ++g) w4[g] = *(const float4*)(wp[g] + hh);
    #pragma unroll
    for (int bi = 0; bi < 16; ++bi) {
      const float4 c4 = *(const float4*)&lds[bi*64 + hh];
      #pragma unroll
      for (int g = 0; g < 4; ++g) {
        acc[g][bi] = fmaf(w4[g].w, c4.w, fmaf(w4[g].z, c4.z,
                     fmaf(w4[g].y, c4.y, fmaf(w4[g].x, c4.x, acc[g][bi]))));
      }
    }
  }

  float* op = out_part + (size_t)hs*OSLICE + (size_t)(bh*16)*CC;
  #pragma unroll
  for (int bi = 0; bi < 16; ++bi) {
    #pragma unroll
    for (int g = 0; g < 4; ++g) {
      if (cc[g] < CC) op[(size_t)bi*CC + cc[g]] = acc[g][bi];
    }
  }
}

// ---------------- k4: sum 8 slices + bias -> d_out --------------------------
__global__ __launch_bounds__(256) void k4_final(
    const float* __restrict__ out_part, const float* __restrict__ ob,
    float* __restrict__ out)
{
  const size_t i = ((size_t)blockIdx.x * 256 + threadIdx.x) * 4;
  float4 r = *(const float4*)(out_part + i);
  #pragma unroll
  for (int q = 1; q < HS; ++q) {
    const float4 p = *(const float4*)(out_part + (size_t)q*OSLICE + i);
    r.x += p.x; r.y += p.y; r.z += p.z; r.w += p.w;
  }
  const int cIdx = (int)(i % CC);
  const float4 b4 = *(const float4*)(ob + cIdx);
  *(float4*)(out + i) = make_float4(r.x+b4.x, r.y+b4.y, r.z+b4.z, r.w+b4.w);
}

extern "C" void kernel_launch(void* const* d_in, const int* in_sizes, int n_in,
                              void* d_out, int out_size, void* d_ws, size_t ws_size,
                              hipStream_t stream) {
  const float* dec = (const float*)d_in[0];
  const float* aw  = (const float*)d_in[1];
  const float* ab  = (const float*)d_in[2];
  const float* ow  = (const float*)d_in[3];
  const float* ob  = (const float*)d_in[4];
  float* out = (float*)d_out;
  float* ws  = (float*)d_ws;
  float* ctx   = ws + WS_CTX;
  float* lpart = ws + WS_LPART;
  float* big   = ws + WS_BIG;   // cpart for k1/k2, reused as opart for k3/k4

  k1_partials<<<dim3(NCHUNK, BB), 256, 0, stream>>>(dec, aw, ab, big, lpart);
  k2_combine<<<dim3(BB), 128, 0, stream>>>(big, lpart, ctx);
  k3_matmul<<<dim3(32, HS, 2), 256, 0, stream>>>(ctx, ow, big);
  k4_final<<<dim3((BB*CC)/(256*4)), 256, 0, stream>>>(big, ob, out);
}

// Round 9
// 89.803 us; speedup vs baseline: 15.8809x; 1.2804x over previous
//
#include <hip/hip_runtime.h>
#include <hip/hip_bf16.h>
#include <math.h>

#define TT 4096
#define BB 32
#define HH 512
#define CC 32000
#define NCHUNK 64   // t-chunks (TT/TPC)
#define TPC 64      // t per chunk (4 waves x 16 rows)
#define HQ 4        // h-quarters in k3
#define OSLICE (BB*CC)  // 1,024,000
#define OW_PAD 36   // LDS row stride (floats); stride/4 = 9 (odd) => conflict-free b128

// ws layout (float offsets)
#define WS_CTX    0          // 16384 floats (k2->k3)
#define WS_LPART  16384      // 2048 floats (k1->k2)
#define WS_BIG    18432      // cpart 1,048,576 f (k1->k2); then opart 4*1,024,000 f (k3->k4)

__device__ __forceinline__ float dot4(const float4 a, const float4 b) {
  return fmaf(a.w, b.w, fmaf(a.z, b.z, fmaf(a.y, b.y, fmaf(a.x, b.x, 0.f))));
}

// ---------------- k1: fused score + weighted partial sums ------------------
// (R6 verbatim -- measured ~33us, near its HBM/L3 floor. Do not touch.)
__global__ __launch_bounds__(256) void k1_partials(
    const float* __restrict__ dec, const float* __restrict__ aw,
    const float* __restrict__ abp,
    float* __restrict__ ctx_part, float* __restrict__ l_part)
{
  const int chunk = blockIdx.x;
  const int b     = blockIdx.y;
  const int tid   = threadIdx.x;
  const int wv = tid >> 6, ln = tid & 63;
  const float ab = abp[0];
  const float4 aw0 = *(const float4*)(aw + ln*4);          // h in [0,256)
  const float4 aw1 = *(const float4*)(aw + 256 + ln*4);    // h in [256,512)

  const size_t rowstep = (size_t)BB*HH;
  const float* base = dec + ((size_t)(chunk*TPC + wv*16)*BB + b)*HH + (size_t)ln*4;

  float4 c0 = make_float4(0.f,0.f,0.f,0.f), c1 = make_float4(0.f,0.f,0.f,0.f);
  float l = 0.f;

  for (int it = 0; it < 16; it += 2) {
    const float* p0 = base + (size_t)it*rowstep;
    const float* p1 = base + (size_t)(it+1)*rowstep;
    const float4 xa0 = *(const float4*)(p0);
    const float4 xa1 = *(const float4*)(p0 + 256);
    const float4 xb0 = *(const float4*)(p1);
    const float4 xb1 = *(const float4*)(p1 + 256);
    float da = dot4(xa0, aw0) + dot4(xa1, aw1);
    float db = dot4(xb0, aw0) + dot4(xb1, aw1);
    #pragma unroll
    for (int off = 32; off > 0; off >>= 1) {
      da += __shfl_xor(da, off);
      db += __shfl_xor(db, off);
    }
    const float exa = __expf(2.f*(da + ab));
    const float exb = __expf(2.f*(db + ab));
    const float tha = 1.f - 2.f*__builtin_amdgcn_rcpf(exa + 1.f);
    const float thb = 1.f - 2.f*__builtin_amdgcn_rcpf(exb + 1.f);
    const float wa = __expf(tha);
    const float wb = __expf(thb);
    l += wa + wb;
    c0.x = fmaf(wa, xa0.x, fmaf(wb, xb0.x, c0.x));
    c0.y = fmaf(wa, xa0.y, fmaf(wb, xb0.y, c0.y));
    c0.z = fmaf(wa, xa0.z, fmaf(wb, xb0.z, c0.z));
    c0.w = fmaf(wa, xa0.w, fmaf(wb, xb0.w, c0.w));
    c1.x = fmaf(wa, xa1.x, fmaf(wb, xb1.x, c1.x));
    c1.y = fmaf(wa, xa1.y, fmaf(wb, xb1.y, c1.y));
    c1.z = fmaf(wa, xa1.z, fmaf(wb, xb1.z, c1.z));
    c1.w = fmaf(wa, xa1.w, fmaf(wb, xb1.w, c1.w));
  }

  __shared__ float s_ctx[4][HH];
  __shared__ float s_l[4];
  *(float4*)&s_ctx[wv][ln*4]       = c0;
  *(float4*)&s_ctx[wv][256 + ln*4] = c1;
  if (ln == 0) s_l[wv] = l;
  __syncthreads();
  if (tid < 128) {
    const int h = tid * 4;
    float4 a = make_float4(0.f,0.f,0.f,0.f);
    #pragma unroll
    for (int w2 = 0; w2 < 4; ++w2) {
      const float4 v = *(const float4*)&s_ctx[w2][h];
      a.x += v.x; a.y += v.y; a.z += v.z; a.w += v.w;
    }
    const size_t pp = (size_t)b*NCHUNK + chunk;
    *(float4*)(ctx_part + pp*HH + h) = a;
    if (tid == 0) l_part[pp] = s_l[0] + s_l[1] + s_l[2] + s_l[3];
  }
}

// ---------------- k2: combine partials -> normalized context ----------------
__global__ __launch_bounds__(128) void k2_combine(
    const float* __restrict__ ctx_part, const float* __restrict__ l_part,
    float* __restrict__ ctx)
{
  const int b = blockIdx.x;
  const int h = threadIdx.x * 4;
  float L = 0.f;
  for (int p = 0; p < NCHUNK; ++p) L += l_part[b*NCHUNK + p];
  float4 a = make_float4(0.f,0.f,0.f,0.f);
  for (int p = 0; p < NCHUNK; ++p) {
    const float4 v = *(const float4*)(ctx_part + ((size_t)b*NCHUNK + p)*HH + h);
    a.x += v.x; a.y += v.y; a.z += v.z; a.w += v.w;
  }
  const float inv = 1.f / L;
  *(float4*)(ctx + b*HH + h) = make_float4(a.x*inv, a.y*inv, a.z*inv, a.w*inv);
}

// ---------------- k3: LDS-tiled GEMM, coalesced ow staging ------------------
// R7/R8 k3 had each lane streaming its own 2KB-strided ow row: every wave
// load = 64 scattered 64B segments in 64 distinct DRAM rows -> ~6% DRAM
// efficiency -> ~50us. Fix: stage ow [256 c][32 h] chunks to LDS with
// CONTIGUOUS global reads; pad LDS stride to 36 f (quad-spread, conflict-
// free b128); ctx slice [32][128] staged once, read broadcast.
// Block 256 thr = 4 waves (b-octets); thread: 4 c-groups x 8 b tile.
__global__ __launch_bounds__(256) void k3_matmul(
    const float* __restrict__ ctx, const float* __restrict__ ow,
    float* __restrict__ out_part)
{
  __shared__ float s_ow[256*OW_PAD];   // 36.9 KB
  __shared__ float s_cx[32*128];       // 16 KB
  const int tid = threadIdx.x;
  const int ci = tid & 63, wv = tid >> 6;
  const int hq = blockIdx.x, cblk = blockIdx.y;
  const int h0 = hq * 128;
  const int crow0 = cblk * 256;

  // stage ctx[:, h0:h0+128] once (coalesced; 4 f4 per thread)
  #pragma unroll
  for (int rep = 0; rep < 4; ++rep) {
    const int j = rep*1024 + tid*4;
    const int b = j >> 7, hh = j & 127;
    *(float4*)&s_cx[j] = *(const float4*)(ctx + (size_t)b*HH + h0 + hh);
  }

  float acc[4][8];
  #pragma unroll
  for (int g = 0; g < 4; ++g)
    #pragma unroll
    for (int bi = 0; bi < 8; ++bi) acc[g][bi] = 0.f;

  for (int ch = 0; ch < 4; ++ch) {
    if (ch) __syncthreads();           // protect s_ow reads of prev chunk
    // stage ow chunk [256 rows][32 h]: 8 f4/thread, contiguous 128B runs/row
    #pragma unroll
    for (int rep = 0; rep < 8; ++rep) {
      const int j = rep*256 + tid;
      const int r = j >> 3, hp = j & 7;
      *(float4*)&s_ow[r*OW_PAD + hp*4] =
          *(const float4*)(ow + (size_t)(crow0 + r)*HH + h0 + ch*32 + hp*4);
    }
    __syncthreads();
    // compute: 8 h-steps x (4 ow b128 + 8 ctx broadcast b128 + 128 FMA)
    #pragma unroll
    for (int s = 0; s < 8; ++s) {
      float4 w4[4];
      #pragma unroll
      for (int g = 0; g < 4; ++g)
        w4[g] = *(const float4*)&s_ow[(g*64 + ci)*OW_PAD + s*4];
      #pragma unroll
      for (int bi = 0; bi < 8; ++bi) {
        const float4 c4 = *(const float4*)&s_cx[(wv*8 + bi)*128 + ch*32 + s*4];
        #pragma unroll
        for (int g = 0; g < 4; ++g) {
          acc[g][bi] = fmaf(w4[g].w, c4.w, fmaf(w4[g].z, c4.z,
                       fmaf(w4[g].y, c4.y, fmaf(w4[g].x, c4.x, acc[g][bi]))));
        }
      }
    }
  }

  // store: b = wv*8+bi, c = crow0 + g*64 + ci (coalesced 256B per instr)
  float* op = out_part + (size_t)hq*OSLICE;
  #pragma unroll
  for (int bi = 0; bi < 8; ++bi) {
    #pragma unroll
    for (int g = 0; g < 4; ++g)
      op[(size_t)(wv*8 + bi)*CC + crow0 + g*64 + ci] = acc[g][bi];
  }
}

// ---------------- k4: sum 4 slices + bias -> d_out --------------------------
__global__ __launch_bounds__(256) void k4_final(
    const float* __restrict__ out_part, const float* __restrict__ ob,
    float* __restrict__ out)
{
  const size_t i = ((size_t)blockIdx.x * 256 + threadIdx.x) * 4;
  float4 r = *(const float4*)(out_part + i);
  #pragma unroll
  for (int q = 1; q < HQ; ++q) {
    const float4 p = *(const float4*)(out_part + (size_t)q*OSLICE + i);
    r.x += p.x; r.y += p.y; r.z += p.z; r.w += p.w;
  }
  const int cIdx = (int)(i % CC);
  const float4 b4 = *(const float4*)(ob + cIdx);
  *(float4*)(out + i) = make_float4(r.x+b4.x, r.y+b4.y, r.z+b4.z, r.w+b4.w);
}

extern "C" void kernel_launch(void* const* d_in, const int* in_sizes, int n_in,
                              void* d_out, int out_size, void* d_ws, size_t ws_size,
                              hipStream_t stream) {
  const float* dec = (const float*)d_in[0];
  const float* aw  = (const float*)d_in[1];
  const float* ab  = (const float*)d_in[2];
  const float* ow  = (const float*)d_in[3];
  const float* ob  = (const float*)d_in[4];
  float* out = (float*)d_out;
  float* ws  = (float*)d_ws;
  float* ctx   = ws + WS_CTX;
  float* lpart = ws + WS_LPART;
  float* big   = ws + WS_BIG;   // cpart for k1/k2, reused as opart for k3/k4

  k1_partials<<<dim3(NCHUNK, BB), 256, 0, stream>>>(dec, aw, ab, big, lpart);
  k2_combine<<<dim3(BB), 128, 0, stream>>>(big, lpart, ctx);
  k3_matmul<<<dim3(HQ, 125), 256, 0, stream>>>(ctx, ow, big);
  k4_final<<<dim3((BB*CC)/(256*4)), 256, 0, stream>>>(big, ob, out);
}